// Round 5
// baseline (119.966 us; speedup 1.0000x reference)
//
#include <hip/hip_runtime.h>

// inputs (8, 512, 96, 2) f32, WIN=10. Output (8, 511, 96, 96) f32 = 150.7 MB.
constexpr int WIN = 10;
constexpr int Bn  = 8;
constexpr int Sn  = 512;
constexpr int An  = 96;
constexpr int Tn  = Sn - 1;          // 511
constexpr int AV  = An * 2;          // 192

constexpr int CH     = 16;           // t-outputs per corr block
constexpr int CHUNKS_PER_B = (Tn + CH - 1) / CH;   // 32
constexpr int MAXROWS = CH + WIN - 1;              // 25 staged s-rows
constexpr int ISPLIT  = 4;                         // i-rows split across blocks
constexpr int ROWS    = An / ISPLIT;               // 24 rows per block
constexpr int NTHR    = 192;
constexpr int TXN     = 24;          // float4-column index 0..23  (j = 4*tx+c)
constexpr int TYN     = NTHR / TXN;  // 8
constexpr int RPT     = ROWS / TYN;  // 3 rows per thread

constexpr int NPROD   = 64;          // producer blocks (8 per batch)
constexpr int PPB     = NPROD / Bn;  // 8
constexpr int PROWS   = Sn / PPB;    // 64 s-rows per producer

// ws layout: [0 .. Bn*AV)  = mean accumulation buffer (atomicAdd target)
//            [Bn*AV]       = release counter (int)
// both zeroed by hipMemsetAsync each call.

__global__ __launch_bounds__(NTHR)
void corr_fused(const float* __restrict__ in, float* __restrict__ ws,
                float* __restrict__ out) {
    __shared__ __align__(16) float xw[MAXROWS * AV];  // 19200 B
    __shared__ __align__(16) float smu[AV];

    float* meanbuf = ws;
    int*   flag    = reinterpret_cast<int*>(ws + Bn * AV);

    const int bid     = blockIdx.x;
    const int b       = bid / (CHUNKS_PER_B * ISPLIT);
    const int rem     = bid - b * (CHUNKS_PER_B * ISPLIT);
    const int chunk   = rem >> 2;            // ISPLIT == 4
    const int quarter = rem & 3;
    const int i0      = quarter * ROWS;

    const int t0 = chunk * CH;
    const int t1 = min(t0 + CH - 1, Tn - 1);
    int sbase = t0 - (WIN - 1); if (sbase < 0) sbase = 0;
    const int nrows = t1 - sbase + 1;        // <= 25

    const int tid = threadIdx.x;

    // ---- producer phase: first 64 blocks build per-b channel sums ----
    if (bid < NPROD) {
        const int pb = bid >> 3;             // batch 0..7
        const int pp = bid & 7;              // slice 0..7
        const float4* src = reinterpret_cast<const float4*>(in)
                          + ((size_t)pb * Sn + pp * PROWS) * (AV / 4);
        const int q  = tid % (AV / 4);       // channel quad 0..47
        const int rg = tid / (AV / 4);       // row group 0..3
        float4 s = make_float4(0.f, 0.f, 0.f, 0.f);
        #pragma unroll
        for (int r = 0; r < PROWS / 4; ++r) {
            float4 v = src[(size_t)(rg + 4 * r) * (AV / 4) + q];
            s.x += v.x; s.y += v.y; s.z += v.z; s.w += v.w;
        }
        float4* red = reinterpret_cast<float4*>(xw);
        red[rg * (AV / 4) + q] = s;
        __syncthreads();
        if (rg == 0) {
            float4 a = red[q], b1 = red[48 + q], c1 = red[96 + q], d1 = red[144 + q];
            a.x += b1.x + c1.x + d1.x;
            a.y += b1.y + c1.y + d1.y;
            a.z += b1.z + c1.z + d1.z;
            a.w += b1.w + c1.w + d1.w;
            atomicAdd(&meanbuf[pb * AV + 4 * q + 0], a.x);
            atomicAdd(&meanbuf[pb * AV + 4 * q + 1], a.y);
            atomicAdd(&meanbuf[pb * AV + 4 * q + 2], a.z);
            atomicAdd(&meanbuf[pb * AV + 4 * q + 3], a.w);
        }
        __threadfence();                     // drain atomics device-wide
        __syncthreads();
        if (tid == 0)
            __hip_atomic_fetch_add(flag, 1, __ATOMIC_RELEASE,
                                   __HIP_MEMORY_SCOPE_AGENT);
        __syncthreads();                     // xw reuse below is safe
    }

    // ---- stage RAW rows [sbase..t1] (overlaps producers' work) ----
    {
        const float4* src4 = reinterpret_cast<const float4*>(in)
                           + ((size_t)(b * Sn + sbase)) * (AV / 4);
        float4* dst = reinterpret_cast<float4*>(xw);
        const int tot4 = nrows * (AV / 4);
        for (int idx = tid; idx < tot4; idx += NTHR) dst[idx] = src4[idx];
    }
    __syncthreads();

    // ---- wait for all producers, then acquire ----
    if (tid == 0) {
        while (__hip_atomic_load(flag, __ATOMIC_ACQUIRE,
                                 __HIP_MEMORY_SCOPE_AGENT) < NPROD)
            __builtin_amdgcn_s_sleep(8);
    }
    __syncthreads();
    __threadfence();                         // invalidate stale cache lines

    // ---- load mean, center staged rows in place ----
    smu[tid] = meanbuf[b * AV + tid] * (1.0f / Sn);
    __syncthreads();
    {
        float4* dst = reinterpret_cast<float4*>(xw);
        const float4* smu4 = reinterpret_cast<const float4*>(smu);
        const int tot4 = nrows * (AV / 4);
        for (int idx = tid; idx < tot4; idx += NTHR) {
            float4 v = dst[idx], m = smu4[idx % (AV / 4)];
            v.x -= m.x; v.y -= m.y; v.z -= m.z; v.w -= m.w;
            dst[idx] = v;
        }
    }
    __syncthreads();

    // ---- sliding-window correlation ----
    const int tx = tid % TXN;   // float4 col: j = 4*tx + c
    const int ty = tid / TXN;   // row group: i = i0 + ty + 8*r

    float acc[RPT][4];
    float di[RPT], dj[4];
    #pragma unroll
    for (int r = 0; r < RPT; ++r) {
        di[r] = 0.f;
        #pragma unroll
        for (int c = 0; c < 4; ++c) acc[r][c] = 0.f;
    }
    #pragma unroll
    for (int c = 0; c < 4; ++c) dj[c] = 0.f;

#define ACCUM(ls, OP)                                                        \
    {                                                                        \
        const float* xs = &xw[(ls) * AV];                                    \
        float4 xj0 = *reinterpret_cast<const float4*>(&xs[8 * tx]);          \
        float4 xj1 = *reinterpret_cast<const float4*>(&xs[8 * tx + 4]);      \
        dj[0] OP (xj0.x * xj0.x + xj0.y * xj0.y);                            \
        dj[1] OP (xj0.z * xj0.z + xj0.w * xj0.w);                            \
        dj[2] OP (xj1.x * xj1.x + xj1.y * xj1.y);                            \
        dj[3] OP (xj1.z * xj1.z + xj1.w * xj1.w);                            \
        _Pragma("unroll")                                                    \
        for (int r = 0; r < RPT; ++r) {                                      \
            float2 xi = *reinterpret_cast<const float2*>(                    \
                &xs[(i0 + ty + 8 * r) * 2]);                                 \
            di[r] OP (xi.x * xi.x + xi.y * xi.y);                            \
            acc[r][0] OP (xi.x * xj0.x + xi.y * xj0.y);                      \
            acc[r][1] OP (xi.x * xj0.z + xi.y * xj0.w);                      \
            acc[r][2] OP (xi.x * xj1.x + xi.y * xj1.y);                      \
            acc[r][3] OP (xi.x * xj1.z + xi.y * xj1.w);                      \
        }                                                                    \
    }

    auto emit = [&](int t) {
        float rsj[4];
        #pragma unroll
        for (int c = 0; c < 4; ++c) rsj[c] = rsqrtf(dj[c]);
        float* ob = out + (size_t)(b * Tn + t) * (An * An);
        #pragma unroll
        for (int r = 0; r < RPT; ++r) {
            int i = i0 + ty + 8 * r;
            float ri = rsqrtf(di[r]);
            float4 v;
            v.x = (i == 4 * tx + 0) ? 0.f : acc[r][0] * ri * rsj[0];
            v.y = (i == 4 * tx + 1) ? 0.f : acc[r][1] * ri * rsj[1];
            v.z = (i == 4 * tx + 2) ? 0.f : acc[r][2] * ri * rsj[2];
            v.w = (i == 4 * tx + 3) ? 0.f : acc[r][3] * ri * rsj[3];
            *reinterpret_cast<float4*>(&ob[(size_t)i * An + 4 * tx]) = v;
        }
    };

    for (int s = sbase; s <= t0; ++s) ACCUM(s - sbase, +=);
    emit(t0);
    for (int t = t0 + 1; t <= t1; ++t) {
        ACCUM(t - sbase, +=);
        if (t >= WIN) ACCUM(t - WIN - sbase, -=);
        emit(t);
    }
#undef ACCUM
}

extern "C" void kernel_launch(void* const* d_in, const int* in_sizes, int n_in,
                              void* d_out, int out_size, void* d_ws, size_t ws_size,
                              hipStream_t stream) {
    const float* in = (const float*)d_in[0];
    float* out = (float*)d_out;
    float* ws  = (float*)d_ws;

    // zero the mean buffer + counter (6148 bytes)
    hipMemsetAsync(d_ws, 0, (Bn * AV + 1) * sizeof(float), stream);
    corr_fused<<<Bn * CHUNKS_PER_B * ISPLIT, NTHR, 0, stream>>>(in, ws, out);
}

// Round 6
// 41.541 us; speedup vs baseline: 2.8879x; 2.8879x over previous
//
#include <hip/hip_runtime.h>

// inputs (8, 512, 96, 2) f32, WIN=10. Output (8, 511, 96, 96) f32 = 150.7 MB.
constexpr int WIN = 10;
constexpr int Bn  = 8;
constexpr int Sn  = 512;
constexpr int An  = 96;
constexpr int Tn  = Sn - 1;          // 511
constexpr int AV  = An * 2;          // 192

constexpr int SCHUNK = 32;           // s-rows per partial-sum block
constexpr int NCH    = Sn / SCHUNK;  // 16
constexpr int CH     = 8;            // t-outputs per corr block
constexpr int CHUNKS_PER_B = (Tn + CH - 1) / CH;   // 64
constexpr int MAXROWS = CH + WIN - 1;              // 17 staged s-rows
constexpr int ISPLIT  = 2;                         // i-rows split across blocks
constexpr int ROWS    = An / ISPLIT;               // 48 rows per block
constexpr int NTHR    = 384;                       // 6 waves/block
constexpr int TXN     = 24;          // float4-column index 0..23  (j = 4*tx+c)
constexpr int TYN     = NTHR / TXN;  // 16
constexpr int RPT     = ROWS / TYN;  // 3 rows per thread

// ---- mean pass: partial sums over 32-s chunks (coalesced) ----
__global__ __launch_bounds__(192)
void partial_kernel(const float* __restrict__ in, float* __restrict__ partial) {
    const int blk = blockIdx.x;              // b * NCH + c
    const int b   = blk / NCH;
    const int c   = blk - b * NCH;
    const int av  = threadIdx.x;             // 0..191
    const float* p = in + ((size_t)(b * Sn + c * SCHUNK)) * AV + av;
    float acc = 0.f;
    #pragma unroll
    for (int s = 0; s < SCHUNK; ++s) acc += p[(size_t)s * AV];
    partial[(size_t)blk * AV + av] = acc;
}

// ---- corr: one block per (b, 8-t chunk, i-half) ----
__global__ __launch_bounds__(NTHR)
void corr_kernel(const float* __restrict__ in, const float* __restrict__ partial,
                 float* __restrict__ out) {
    __shared__ __align__(16) float xw[MAXROWS * AV];  // 13056 B
    __shared__ __align__(16) float smu[AV];

    const int bid   = blockIdx.x;
    const int b     = bid / (CHUNKS_PER_B * ISPLIT);
    const int rem   = bid - b * (CHUNKS_PER_B * ISPLIT);
    const int chunk = rem >> 1;              // ISPLIT == 2
    const int half  = rem & 1;
    const int i0    = half * ROWS;

    const int t0 = chunk * CH;
    const int t1 = min(t0 + CH - 1, Tn - 1);
    int sbase = t0 - (WIN - 1); if (sbase < 0) sbase = 0;
    const int nrows = t1 - sbase + 1;        // <= 17

    const int tid = threadIdx.x;

    // --- reduce 16 partials -> mean, in LDS ---
    if (tid < AV) {
        const float* pp = partial + (size_t)b * NCH * AV + tid;
        float acc = 0.f;
        #pragma unroll
        for (int c = 0; c < NCH; ++c) acc += pp[(size_t)c * AV];
        smu[tid] = acc * (1.0f / Sn);
    }
    __syncthreads();

    // --- stage rows [sbase..t1], centered, float4-vectorized ---
    {
        const float4* src = reinterpret_cast<const float4*>(
            in + ((size_t)(b * Sn + sbase)) * AV);
        const float4* mb4 = reinterpret_cast<const float4*>(smu);
        float4* dst = reinterpret_cast<float4*>(xw);
        const int tot4 = nrows * (AV / 4);
        for (int idx = tid; idx < tot4; idx += NTHR) {
            int av4 = idx % (AV / 4);
            float4 v = src[idx], m = mb4[av4];
            v.x -= m.x; v.y -= m.y; v.z -= m.z; v.w -= m.w;
            dst[idx] = v;
        }
    }
    __syncthreads();

    const int tx = tid % TXN;   // float4 col: j = 4*tx + c
    const int ty = tid / TXN;   // row group: i = i0 + ty + 16*r

    float acc[RPT][4];
    float di[RPT], dj[4];
    #pragma unroll
    for (int r = 0; r < RPT; ++r) {
        di[r] = 0.f;
        #pragma unroll
        for (int c = 0; c < 4; ++c) acc[r][c] = 0.f;
    }
    #pragma unroll
    for (int c = 0; c < 4; ++c) dj[c] = 0.f;

#define ACCUM(ls, OP)                                                        \
    {                                                                        \
        const float* xs = &xw[(ls) * AV];                                    \
        float4 xj0 = *reinterpret_cast<const float4*>(&xs[8 * tx]);          \
        float4 xj1 = *reinterpret_cast<const float4*>(&xs[8 * tx + 4]);      \
        dj[0] OP (xj0.x * xj0.x + xj0.y * xj0.y);                            \
        dj[1] OP (xj0.z * xj0.z + xj0.w * xj0.w);                            \
        dj[2] OP (xj1.x * xj1.x + xj1.y * xj1.y);                            \
        dj[3] OP (xj1.z * xj1.z + xj1.w * xj1.w);                            \
        _Pragma("unroll")                                                    \
        for (int r = 0; r < RPT; ++r) {                                      \
            float2 xi = *reinterpret_cast<const float2*>(                    \
                &xs[(i0 + ty + 16 * r) * 2]);                                \
            di[r] OP (xi.x * xi.x + xi.y * xi.y);                            \
            acc[r][0] OP (xi.x * xj0.x + xi.y * xj0.y);                      \
            acc[r][1] OP (xi.x * xj0.z + xi.y * xj0.w);                      \
            acc[r][2] OP (xi.x * xj1.x + xi.y * xj1.y);                      \
            acc[r][3] OP (xi.x * xj1.z + xi.y * xj1.w);                      \
        }                                                                    \
    }

    // normalize + mask + store one t (one float4 store per r, ~1KB/wave-instr)
    auto emit = [&](int t) {
        float rsj[4];
        #pragma unroll
        for (int c = 0; c < 4; ++c) rsj[c] = rsqrtf(dj[c]);
        float* ob = out + (size_t)(b * Tn + t) * (An * An);
        #pragma unroll
        for (int r = 0; r < RPT; ++r) {
            int i = i0 + ty + 16 * r;
            float ri = rsqrtf(di[r]);
            float4 v;
            v.x = (i == 4 * tx + 0) ? 0.f : acc[r][0] * ri * rsj[0];
            v.y = (i == 4 * tx + 1) ? 0.f : acc[r][1] * ri * rsj[1];
            v.z = (i == 4 * tx + 2) ? 0.f : acc[r][2] * ri * rsj[2];
            v.w = (i == 4 * tx + 3) ? 0.f : acc[r][3] * ri * rsj[3];
            *reinterpret_cast<float4*>(&ob[(size_t)i * An + 4 * tx]) = v;
        }
    };

    // --- warm-up: full window sum for t0 ---
    for (int s = sbase; s <= t0; ++s) ACCUM(s - sbase, +=);
    emit(t0);

    // --- slide: W(t) = W(t-1) + g(t) - g(t-WIN) ---
    for (int t = t0 + 1; t <= t1; ++t) {
        ACCUM(t - sbase, +=);
        if (t >= WIN) ACCUM(t - WIN - sbase, -=);
        emit(t);
    }
#undef ACCUM
}

extern "C" void kernel_launch(void* const* d_in, const int* in_sizes, int n_in,
                              void* d_out, int out_size, void* d_ws, size_t ws_size,
                              hipStream_t stream) {
    const float* in = (const float*)d_in[0];
    float* out = (float*)d_out;
    float* partial = (float*)d_ws;    // Bn*NCH*AV = 24576 floats

    partial_kernel<<<Bn * NCH, 192, 0, stream>>>(in, partial);
    corr_kernel<<<Bn * CHUNKS_PER_B * ISPLIT, NTHR, 0, stream>>>(in, partial, out);
}